// Round 7
// baseline (194.277 us; speedup 1.0000x reference)
//
#include <hip/hip_runtime.h>
#include <hip/hip_bf16.h>
#include <math.h>

// Problem constants (from reference)
constexpr int   NC      = 181;        // NUM_CLASSES
constexpr int   BATCH   = 131072;
constexpr float MODC    = 6.2831853071795864769f;   // 2*pi
constexpr float HALFMOD = 3.1415926535897932385f;   // pi
constexpr float DEG2RAD = 0.017453292519943295f;    // pi/180

// magic divide by 181: exact for g < 25.87M (we need g < 46336)
constexpr unsigned MAGIC181 = 23729102u;

// One 256-thread block owns 64 rows = 46336 B of contiguous labels,
// staged into LDS via global_load_lds_dwordx4 (async, no dest VGPRs —
// compiler cannot serialize it). 46 wave-ops/block, 11-12 per wave,
// all in flight. Scan runs from LDS; deposits go to a 2 KB LDS bitmap.
constexpr int RPB   = 64;                    // rows per block
constexpr int WINT4 = RPB * NC / 4;          // 2896 int4 per block window
constexpr int NOPS  = (WINT4 + 63) / 64;     // 46 wave-level x4 ops
constexpr int OPW   = (NOPS + 3) / 4;        // 12 op slots per wave

__device__ __forceinline__ float sq_mod_diff(float x) {
    // d = mod(x + pi, 2pi) - pi;  return d*d   (floored mod, matches jnp.mod)
    float t = x + HALFMOD;
    float m = t - floorf(t * (1.0f / MODC)) * MODC;
    float d = m - HALFMOD;
    return d * d;
}

__global__ __launch_bounds__(256) void fused_kernel(
    const float* __restrict__ logits,
    const int*   __restrict__ labels,
    float*       __restrict__ out)
{
    __shared__ int4     win[WINT4];     // 45.25 KB staged label window
    __shared__ unsigned bm[RPB * 8];    // 2 KB: 64 rows x 256-bit bitmap

    const int tid  = threadIdx.x;
    const int lane = tid & 63;
    const int w    = tid >> 6;
    const int rowBase = blockIdx.x * RPB;

    // ---- zero LDS bitmap (512 words, 2 per thread) ----
    bm[tid]       = 0u;
    bm[tid + 256] = 0u;

    // ---- issue logits loads early (consumed after the barrier) ----
    float d0 = 0.f, d1 = 0.f, d2 = 0.f, d3 = 0.f;
    if (tid < RPB) {
        const float* lp = logits + (size_t)(rowBase + tid) * NC;
        d0 = lp[0]; d1 = lp[1]; d2 = lp[2]; d3 = lp[3];
    }

    // ---- async stage: 46 global_load_lds_dwordx4 wave-ops, fire-and-forget ----
    const int4* gbase = (const int4*)labels + (size_t)blockIdx.x * WINT4;
    #pragma unroll
    for (int k = 0; k < OPW; ++k) {
        const int op = w * OPW + k;          // wave w owns ops [w*12, w*12+12)
        if (op < NOPS) {
            const int x4 = op * 64 + lane;   // lane-linear within the op
            if (x4 < WINT4) {                // tail op: lanes 0..15 active
                __builtin_amdgcn_global_load_lds(
                    (const __attribute__((address_space(1))) void*)(gbase + x4),
                    (__attribute__((address_space(3))) void*)(&win[x4]),
                    16, 0, 0);
            }
        }
    }
    __syncthreads();   // drains vmcnt(0): window + logits resident; bm zeroed

    // ---- scan from LDS + bitmap deposit (block-local indices) ----
    #pragma unroll
    for (int k = 0; k < OPW; ++k) {
        const int idx = tid + 256 * k;
        if (idx < WINT4) {
            const int4 v = win[idx];
            if ((v.x | v.y | v.z | v.w) != 0) {
                const unsigned g0 = (unsigned)idx * 4u;
                #pragma unroll
                for (int c = 0; c < 4; ++c) {
                    const int comp = (c == 0) ? v.x : (c == 1) ? v.y
                                   : (c == 2) ? v.z : v.w;
                    if (comp != 0) {
                        const unsigned g   = g0 + (unsigned)c;
                        const unsigned row = __umulhi(g, MAGIC181);  // g/181
                        const unsigned cls = g - 181u * row;         // g%181
                        atomicOr(&bm[row * 8u + (cls >> 5u)],
                                 1u << (cls & 31u));                 // LDS ds_or
                    }
                }
            }
        }
    }
    __syncthreads();

    // ---- compute phase: wave 0, one row per lane ----
    if (tid < RPB) {
        const float doa[4] = {d0, d1, d2, d3};

        float ang[4];
        int found = 0;
        #pragma unroll
        for (int k = 0; k < 8; ++k) {
            unsigned mm = bm[tid * 8 + k];
            while (mm) {
                const int j = __builtin_ctz(mm);
                mm &= mm - 1;
                ang[found & 3] = ((float)(k * 32 + j) - 90.0f) * DEG2RAD;
                ++found;
            }
        }

        float cst[4][4];
        #pragma unroll
        for (int i = 0; i < 4; ++i)
            #pragma unroll
            for (int j = 0; j < 4; ++j)
                cst[i][j] = sq_mod_diff(doa[i] - ang[j]);

        float best = 1e30f;
        #pragma unroll
        for (int a = 0; a < 4; ++a) {
            #pragma unroll
            for (int b = 0; b < 4; ++b) {
                if (b == a) continue;
                const float top = cst[0][a] + cst[1][b];
                #pragma unroll
                for (int e = 0; e < 4; ++e) {
                    if (e == a || e == b) continue;
                    const int f = 6 - a - b - e;
                    best = fminf(best, top + cst[2][e] + cst[3][f]);
                }
            }
        }
        float sum = sqrtf(best * 0.25f);

        // wave 0 reduce (64 fully-active lanes) -> one atomic per block
        #pragma unroll
        for (int off = 32; off > 0; off >>= 1)
            sum += __shfl_down(sum, off);
        if (lane == 0)
            atomicAdd(out, sum * (1.0f / (float)BATCH));   // 2048 atomics
    }
}

extern "C" void kernel_launch(void* const* d_in, const int* in_sizes, int n_in,
                              void* d_out, int out_size, void* d_ws, size_t ws_size,
                              hipStream_t stream) {
    const float* logits = (const float*)d_in[0];
    const int*   labels = (const int*)d_in[1];
    float*       out    = (float*)d_out;

    // d_out is poisoned (0xAA) before every launch — zero it first.
    hipMemsetAsync(out, 0, sizeof(float), stream);

    // BATCH / RPB = 2048 blocks x 256 threads
    fused_kernel<<<BATCH / RPB, 256, 0, stream>>>(logits, labels, out);
}

// Round 8
// 189.055 us; speedup vs baseline: 1.0276x; 1.0276x over previous
//
#include <hip/hip_runtime.h>
#include <hip/hip_bf16.h>
#include <math.h>

// Problem constants (from reference)
constexpr int   NC      = 181;        // NUM_CLASSES
constexpr int   BATCH   = 131072;
constexpr float MODC    = 6.2831853071795864769f;   // 2*pi
constexpr float HALFMOD = 3.1415926535897932385f;   // pi
constexpr float DEG2RAD = 0.017453292519943295f;    // pi/180

// magic divide by 181: exact well past g = 46336 (max window int index)
constexpr unsigned MAGIC181 = 23729102u;

// One 256-thread block owns 64 rows = 2896 int4 of contiguous labels.
// Phase 1 is BRANCH-FREE: batched int4 loads -> sched_barrier -> 4-bit
// nonzero-mask byte per int4 -> LDS. (Branchy consumption is what made
// the compiler sink loads to VGPR_Count=20 and serialize all prior
// versions at ~1 load in flight.)
constexpr int RPB   = 64;                    // rows per block
constexpr int WINT4 = RPB * NC / 4;          // 2896 int4 per block window
constexpr int FULL  = WINT4 / 256;           // 11 full int4 per thread
constexpr int TAIL  = WINT4 - FULL * 256;    // 80 tail int4
constexpr int MB4   = WINT4 / 4;             // 724 mask dwords

__device__ __forceinline__ float sq_mod_diff(float x) {
    // d = mod(x + pi, 2pi) - pi;  return d*d   (floored mod, matches jnp.mod)
    float t = x + HALFMOD;
    float m = t - floorf(t * (1.0f / MODC)) * MODC;
    float d = m - HALFMOD;
    return d * d;
}

__global__ __launch_bounds__(256) void fused_kernel(
    const float* __restrict__ logits,
    const int*   __restrict__ labels,
    float*       __restrict__ out)
{
    __shared__ unsigned char smask[WINT4];   // 2896 B: 1 mask byte / int4
    __shared__ unsigned      bm[RPB * 8];    // 2 KB: 64 rows x 256-bit bitmap

    const int tid  = threadIdx.x;
    const int lane = tid & 63;

    // ---- zero LDS bitmap (512 words, 2 per thread) ----
    bm[tid]       = 0u;
    bm[tid + 256] = 0u;

    // ---- logits prefetch (consumed in phase 3) ----
    float d0 = 0.f, d1 = 0.f, d2 = 0.f, d3 = 0.f;
    if (tid < RPB) {
        const float* lp = logits + (size_t)(blockIdx.x * RPB + tid) * NC;
        d0 = lp[0]; d1 = lp[1]; d2 = lp[2]; d3 = lp[3];
    }

    // ---- phase 1: batched loads (branch-free consumption) ----
    const int4* gbase = (const int4*)labels + (size_t)blockIdx.x * WINT4;
    int4 v[FULL];
    #pragma unroll
    for (int k = 0; k < FULL; ++k)
        v[k] = gbase[tid + 256 * k];
    int4 vt = {0, 0, 0, 0};
    if (tid < TAIL) vt = gbase[tid + 256 * FULL];

    __builtin_amdgcn_sched_barrier(0);   // all loads issued before any use

    #pragma unroll
    for (int k = 0; k < FULL; ++k) {
        const unsigned m = (unsigned)(v[k].x != 0)
                         | ((unsigned)(v[k].y != 0) << 1)
                         | ((unsigned)(v[k].z != 0) << 2)
                         | ((unsigned)(v[k].w != 0) << 3);
        smask[tid + 256 * k] = (unsigned char)m;
    }
    if (tid < TAIL) {
        const unsigned m = (unsigned)(vt.x != 0)
                         | ((unsigned)(vt.y != 0) << 1)
                         | ((unsigned)(vt.z != 0) << 2)
                         | ((unsigned)(vt.w != 0) << 3);
        smask[tid + 256 * FULL] = (unsigned char)m;
    }
    __syncthreads();

    // ---- phase 2: scan mask words from LDS, deposit into bitmap ----
    #pragma unroll
    for (int k = 0; k < 3; ++k) {
        const int idx = tid + 256 * k;           // mask dword index
        if (idx < MB4) {
            unsigned mw = ((const unsigned*)smask)[idx];
            while (mw) {
                const int bit = __builtin_ctz(mw);   // bit = 8*b + c (c<4)
                mw &= mw - 1;
                const unsigned g   = (unsigned)idx * 16u
                                   + ((unsigned)bit >> 3) * 4u
                                   + ((unsigned)bit & 7u);   // int index in window
                const unsigned row = __umulhi(g, MAGIC181);  // g / 181
                const unsigned cls = g - 181u * row;         // g % 181
                atomicOr(&bm[row * 8u + (cls >> 5u)], 1u << (cls & 31u));
            }
        }
    }
    __syncthreads();

    // ---- phase 3: wave 0, one row per lane ----
    if (tid < RPB) {
        const float doa[4] = {d0, d1, d2, d3};

        float ang[4];
        int found = 0;
        #pragma unroll
        for (int k = 0; k < 8; ++k) {
            unsigned mm = bm[tid * 8 + k];
            while (mm) {
                const int j = __builtin_ctz(mm);
                mm &= mm - 1;
                ang[found & 3] = ((float)(k * 32 + j) - 90.0f) * DEG2RAD;
                ++found;
            }
        }

        float cst[4][4];
        #pragma unroll
        for (int i = 0; i < 4; ++i)
            #pragma unroll
            for (int j = 0; j < 4; ++j)
                cst[i][j] = sq_mod_diff(doa[i] - ang[j]);

        float best = 1e30f;
        #pragma unroll
        for (int a = 0; a < 4; ++a) {
            #pragma unroll
            for (int b = 0; b < 4; ++b) {
                if (b == a) continue;
                const float top = cst[0][a] + cst[1][b];
                #pragma unroll
                for (int e = 0; e < 4; ++e) {
                    if (e == a || e == b) continue;
                    const int f = 6 - a - b - e;
                    best = fminf(best, top + cst[2][e] + cst[3][f]);
                }
            }
        }
        float sum = sqrtf(best * 0.25f);

        // wave 0 reduce (64 fully-active lanes) -> one atomic per block
        #pragma unroll
        for (int off = 32; off > 0; off >>= 1)
            sum += __shfl_down(sum, off);
        if (lane == 0)
            atomicAdd(out, sum * (1.0f / (float)BATCH));   // 2048 atomics
    }
}

extern "C" void kernel_launch(void* const* d_in, const int* in_sizes, int n_in,
                              void* d_out, int out_size, void* d_ws, size_t ws_size,
                              hipStream_t stream) {
    const float* logits = (const float*)d_in[0];
    const int*   labels = (const int*)d_in[1];
    float*       out    = (float*)d_out;

    // d_out is poisoned (0xAA) before every launch — zero it first.
    hipMemsetAsync(out, 0, sizeof(float), stream);

    // BATCH / RPB = 2048 blocks x 256 threads
    fused_kernel<<<BATCH / RPB, 256, 0, stream>>>(logits, labels, out);
}